// Round 14
// baseline (309.831 us; speedup 1.0000x reference)
//
#include <hip/hip_runtime.h>

#define BB 8
#define NN 512
#define HH 256
#define NHEADS 8

typedef __attribute__((ext_vector_type(8))) short bf16x8;
typedef __attribute__((ext_vector_type(4))) float f32x4;

// ---------- helpers ----------
__device__ __forceinline__ unsigned f2bf(float f) {
  unsigned u = __float_as_uint(f);
  u += 0x7fffu + ((u >> 16) & 1u);          // round-to-nearest-even
  return u >> 16;
}
__device__ __forceinline__ float bf2f(unsigned short v) {
  return __uint_as_float(((unsigned)v) << 16);
}
// agent-scope coherent (non-fencing) load/store: pair with device-scope atomicAdd data path
__device__ __forceinline__ float cohl(const float* p) {
  return __hip_atomic_load(p, __ATOMIC_RELAXED, __HIP_MEMORY_SCOPE_AGENT);
}
__device__ __forceinline__ void cohs(float* p, float v) {
  __hip_atomic_store(p, v, __ATOMIC_RELAXED, __HIP_MEMORY_SCOPE_AGENT);
}

// ---------- kernel 0: prologue: init x/x_bf | adjacency | transpose W |
// zero asrc/adst (3 layer buffers) + out_acc + counters ----------
__global__ __launch_bounds__(256) void prologue_kernel(const float* __restrict__ emb,
                                                       const int* __restrict__ mask,
                                                       const float* __restrict__ W,
                                                       float* __restrict__ x,
                                                       unsigned short* __restrict__ x_bf,
                                                       unsigned long long* __restrict__ adjT,
                                                       unsigned short* __restrict__ Wt,
                                                       float* __restrict__ asrcT,
                                                       float* __restrict__ adstT,
                                                       float* __restrict__ out_acc,
                                                       unsigned* __restrict__ cnt) {
  __shared__ float s[64][65];
  __shared__ unsigned short sadj[4][64];
  const int bid = blockIdx.x;
  const int t = threadIdx.x;
  if (bid < 1024) {                        // ---- init x (f32) + x_bf (bf16), XCD-pinned by b ----
    const int b = bid & 7, chunk = bid >> 3;           // 128 chunks per b
    const size_t i4 = ((size_t)b * 128 + chunk) * 256 + t;   // float4 index
    const float4 v = ((const float4*)emb)[i4];
    ((float4*)x)[i4] = v;
    uint2 p;
    p.x = f2bf(v.x) | (f2bf(v.y) << 16);
    p.y = f2bf(v.z) | (f2bf(v.w) << 16);
    ((uint2*)x_bf)[i4] = p;
  } else if (bid < 1536) {                 // ---- adjT[b][j][w] bit q <=> edge i=64w+q -> j ----
    const int bb = bid - 1024;             // 512 blocks = (b = bb&7, w, jc)
    const int b = bb & 7, w = (bb >> 3) & 7, jc = bb >> 6;
    const int jloc = t & 63, qq = t >> 6;  // 4 q-quarters of 16
    const int j = jc * 64 + jloc;
    unsigned short bits = 0;
#pragma unroll
    for (int qi = 0; qi < 16; ++qi) {
      const int q = qq * 16 + qi;
      const int i = w * 64 + q;
      const int m = mask[((size_t)b * NN + i) * NN + j];   // coalesced across jloc
      if (m != 0 || i == j) bits |= (unsigned short)(1u << qi);
    }
    sadj[qq][jloc] = bits;
    __syncthreads();
    if (t < 64) {
      const unsigned long long word = (unsigned long long)sadj[0][t] |
                                      ((unsigned long long)sadj[1][t] << 16) |
                                      ((unsigned long long)sadj[2][t] << 32) |
                                      ((unsigned long long)sadj[3][t] << 48);
      adjT[((size_t)b * NN + jc * 64 + t) * 8 + w] = word;
    }
  } else if (bid < 1920) {                 // ---- Wt[l][hk][c] (bf16) = W[l][c][hk] ----
    const int wb = bid - 1536;
    const int l = wb >> 7;
    const int r = wb & 127;
    const int mt = r & 31, ct = r >> 5;
    const int hk0 = mt * 64, c0 = ct * 64;
    const int tr = t >> 6, tc = t & 63;
#pragma unroll
    for (int p = 0; p < 16; ++p) {
      const int row = p * 4 + tr;
      s[row][tc] = W[(size_t)l * 524288 + (size_t)(c0 + row) * 2048 + hk0 + tc];
    }
    __syncthreads();
#pragma unroll
    for (int p = 0; p < 16; ++p) {
      const int hkl = p * 4 + tr;
      Wt[(size_t)l * 524288 + (size_t)(hk0 + hkl) * 256 + c0 + tc] =
          (unsigned short)f2bf(s[tc][hkl]);
    }
  } else {                                 // ---- zero asrc/adst (3 layers), out_acc, counters ----
    const int i4 = (bid - 1920) * 256 + t;           // f4 slots
    const float4 z = {0.f, 0.f, 0.f, 0.f};
    if (i4 < 24576)       ((float4*)asrcT)[i4] = z;
    else if (i4 < 49152)  ((float4*)adstT)[i4 - 24576] = z;
    else                  ((float4*)out_acc)[i4 - 49152] = z;   // 262144 f4
    if (bid == 1920 && t < 64) cnt[t] = 0u;
  }
}

// ---------- kernel 1: proj via MFMA + fused a_src/a_dst partial reduction ----------
// Double-buffered LDS: ONE barrier per K-step. Coalesced C-store via LDS restage.
// grid 512 = (b:8, mt:16, nt:4). 128x128 tile, K=256 in 8 steps of 32. 4 waves 64x64.
__global__ __launch_bounds__(256, 2) void proj_mfma_kernel(const unsigned short* __restrict__ Wt_l,
                                                           const unsigned short* __restrict__ x_bf,
                                                           const float* __restrict__ att_src_l,
                                                           const float* __restrict__ att_dst_l,
                                                           unsigned short* __restrict__ xpTT,
                                                           float* __restrict__ asrcT_l,
                                                           float* __restrict__ adstT_l) {
  __shared__ __align__(16) unsigned char lds[32768];   // [buf:2][A 8KB | B 8KB]; reused as C tile
  const int t = threadIdx.x;
  const int lane = t & 63, wave = t >> 6;
  const int wj = wave >> 1, wk = wave & 1;

  const int bid = blockIdx.x;
  const int b = bid & 7;                  // same-b -> same XCD L2 as agg consumer
  const int r = bid >> 3;
  const int mt = r & 15, nt = r >> 4;
  const int hk0 = mt * 128, n0 = nt * 128;

  const int tr = t >> 1, th = t & 1;
  const size_t aBase = (size_t)(hk0 + tr) * 256 + th * 16;
  const size_t bBase = ((size_t)(b * NN + n0 + tr)) * 256 + th * 16;
  const unsigned sw_w = ((tr >> 1) & 3) << 4;
  const unsigned w0 = tr * 64 + ((th * 32 + 0) ^ sw_w);
  const unsigned w1 = tr * 64 + ((th * 32 + 16) ^ sw_w);

  uint4 ra0, ra1, rb0, rb1;
  {
    ra0 = *(const uint4*)(Wt_l + aBase);
    ra1 = *(const uint4*)(Wt_l + aBase + 8);
    rb0 = *(const uint4*)(x_bf + bBase);
    rb1 = *(const uint4*)(x_bf + bBase + 8);
  }

  const f32x4 z4 = {0.f, 0.f, 0.f, 0.f};
  f32x4 acc[4][4];
#pragma unroll
  for (int fr = 0; fr < 4; ++fr)
#pragma unroll
    for (int fc = 0; fc < 4; ++fc) acc[fr][fc] = z4;

  for (int s = 0; s < 8; ++s) {
    const unsigned boff = (s & 1) << 14;               // 0 / 16384
    *(uint4*)(lds + boff + w0) = ra0;                  // A
    *(uint4*)(lds + boff + w1) = ra1;
    *(uint4*)(lds + boff + 8192 + w0) = rb0;           // B
    *(uint4*)(lds + boff + 8192 + w1) = rb1;
    __syncthreads();
    if (s < 7) {
      const size_t off = (size_t)(s + 1) * 32;
      ra0 = *(const uint4*)(Wt_l + aBase + off);
      ra1 = *(const uint4*)(Wt_l + aBase + off + 8);
      rb0 = *(const uint4*)(x_bf + bBase + off);
      rb1 = *(const uint4*)(x_bf + bBase + off + 8);
    }
    bf16x8 af[4], bfr[4];
#pragma unroll
    for (int fr = 0; fr < 4; ++fr) {
      const int rA = wj * 64 + fr * 16 + (lane & 15);
      af[fr] = *(const bf16x8*)(lds + boff + rA * 64 +
                                (((lane >> 4) * 16) ^ (((rA >> 1) & 3) << 4)));
    }
#pragma unroll
    for (int fc = 0; fc < 4; ++fc) {
      const int rB = wk * 64 + fc * 16 + (lane & 15);
      bfr[fc] = *(const bf16x8*)(lds + boff + 8192 + rB * 64 +
                                 (((lane >> 4) * 16) ^ (((rB >> 1) & 3) << 4)));
    }
#pragma unroll
    for (int fr = 0; fr < 4; ++fr)
#pragma unroll
      for (int fc = 0; fc < 4; ++fc)
        acc[fr][fc] = __builtin_amdgcn_mfma_f32_16x16x32_bf16(af[fr], bfr[fc], acc[fr][fc], 0, 0, 0);
  }

  // ---- restage C tile (bf16) into LDS, then write coalesced rows ----
  __syncthreads();                         // all waves done reading K-loop LDS
  unsigned short* sc = (unsigned short*)lds;           // [128 rows][128 cols] = 32 KB
  const int lr = lane & 15, lo = lane >> 4;
#pragma unroll
  for (int fr = 0; fr < 4; ++fr) {
    const int rowl0 = wj * 64 + fr * 16 + lo * 4;
#pragma unroll
    for (int fc = 0; fc < 4; ++fc) {
      const int coll = wk * 64 + fc * 16 + lr;
#pragma unroll
      for (int rr = 0; rr < 4; ++rr)
        sc[(rowl0 + rr) * 128 + coll] = (unsigned short)f2bf(acc[fr][fc][rr]);
    }
  }
  __syncthreads();
  unsigned short* xpb = xpTT + (size_t)b * 2048 * NN;
#pragma unroll
  for (int p = 0; p < 8; ++p) {
    const int idx4 = p * 256 + t;          // uint4 index in tile (2048 total)
    const int row = idx4 >> 4;             // 16 uint4 per 128-col row
    const int c4 = idx4 & 15;
    *(uint4*)(xpb + (size_t)(hk0 + row) * NN + n0 + c4 * 8) = *(const uint4*)(sc + idx4 * 8);
  }

  // ---- fused a_src/a_dst: block covers head h = mt>>1 (128 hk rows within one head) ----
  float wsv[4][4], wdv[4][4];
#pragma unroll
  for (int fr = 0; fr < 4; ++fr) {
    const int row0 = hk0 + wj * 64 + fr * 16 + lo * 4;
#pragma unroll
    for (int rr = 0; rr < 4; ++rr) {
      wsv[fr][rr] = att_src_l[row0 + rr];
      wdv[fr][rr] = att_dst_l[row0 + rr];
    }
  }
  const int bh = b * 8 + (mt >> 1);
#pragma unroll
  for (int fc = 0; fc < 4; ++fc) {
    float as = 0.f, ad = 0.f;
#pragma unroll
    for (int fr = 0; fr < 4; ++fr)
#pragma unroll
      for (int rr = 0; rr < 4; ++rr) {
        as = fmaf(acc[fr][fc][rr], wsv[fr][rr], as);
        ad = fmaf(acc[fr][fc][rr], wdv[fr][rr], ad);
      }
    as += __shfl_xor(as, 16);
    as += __shfl_xor(as, 32);
    ad += __shfl_xor(ad, 16);
    ad += __shfl_xor(ad, 32);
    if ((lane >> 4) == 0) {
      const int col = n0 + wk * 64 + fc * 16 + lane;   // lane in [0,16)
      atomicAdd(&asrcT_l[(size_t)bh * NN + col], as);
      atomicAdd(&adstT_l[(size_t)bh * NN + col], ad);
    }
  }
}

// ---------- kernel 2: fused agg + atomic head-accumulation + group-tail epilogue ----------
// grid 512 = (b:8, jt:8, hs:8). 64j x 256k tile, K=512 in 16 steps. 4 waves wk:4.
// Heads accumulate into f32 out_acc via device-scope atomicAdd (per-line, no bulk fence).
// Per-(b,jt) group of 8 hs-blocks: 8th arrival (relaxed atomic counter; __syncthreads has
// already drained each wave's vmcnt, so all data atomics are globally performed) runs the
// epilogue for its 64 rows. mode 0/1: x += relu(sum+bias); mode 2: residual + LayerNorm.
__global__ __launch_bounds__(256, 2) void agg_fused_kernel(const unsigned short* __restrict__ xpTT,
                                                           const float* __restrict__ asrcT_l,
                                                           const float* __restrict__ adstT_l,
                                                           const unsigned long long* __restrict__ adjT,
                                                           float* __restrict__ out_acc,
                                                           const float* __restrict__ bias_l,
                                                           float* __restrict__ x,
                                                           unsigned short* __restrict__ x_bf,
                                                           const float* __restrict__ emb,
                                                           const float* __restrict__ gamma,
                                                           const float* __restrict__ beta,
                                                           float* __restrict__ out,
                                                           unsigned* __restrict__ cnt,
                                                           const int mode) {
  __shared__ __align__(16) unsigned char lds[40960];    // [buf:2][A 4KB | B 16KB]
  __shared__ float s_as[NN];                            // a_src, head hs
  __shared__ __align__(16) unsigned char s_adjw[4096];  // adjacency rows j0..j0+64 (64 B each)
  __shared__ float s_dinv[64];
  __shared__ float s_mu[64], s_rsig[64];
  __shared__ int s_last;
  const int t = threadIdx.x;
  const int lane = t & 63, wave = t >> 6;
  const int wk = wave;                    // wave owns k-columns wk*64..wk*64+64

  const int bid = blockIdx.x;
  const int b = bid & 7;
  const int r = bid >> 3;
  const int jt = r & 7, hs = r >> 3;
  const int j0 = jt * 64;
  const int bh = b * 8 + hs;

  const int tr4 = t >> 2, th4 = t & 3;   // A staging + GENP: row tr4 (0..63), i-octet th4
  const int tr2 = t >> 1, th2 = t & 1;   // B staging: rows tr2 and tr2+128, i-half th2

  // stage a_src + adjacency rows
  s_as[t] = asrcT_l[(size_t)bh * NN + t];
  s_as[t + 256] = asrcT_l[(size_t)bh * NN + t + 256];
  *(uint4*)(s_adjw + tr4 * 64 + th4 * 16) =
      *(const uint4*)((const unsigned char*)adjT + ((size_t)(b * NN + j0 + tr4)) * 64 + th4 * 16);
  const float adv = adstT_l[(size_t)bh * NN + j0 + tr4];
  __syncthreads();

  const unsigned sw4 = ((tr4 >> 1) & 3) << 4;
  const unsigned wA = tr4 * 64 + ((th4 * 16) ^ sw4);
  const unsigned sw2 = ((tr2 >> 1) & 3) << 4;          // same swizzle for row tr2 and tr2+128
  const unsigned wB0 = tr2 * 64 + ((th2 * 32 + 0) ^ sw2);
  const unsigned wB1 = tr2 * 64 + ((th2 * 32 + 16) ^ sw2);
  const size_t bBase0 = ((size_t)bh * HH + tr2) * NN + th2 * 16;        // row tr2
  const size_t bBase1 = ((size_t)bh * HH + tr2 + 128) * NN + th2 * 16;  // row tr2+128

  float esum = 0.f;                       // running denominator, row tr4, this th4 i-octet set
  uint4 pe, rb0, rb1, rb2, rb3;
  auto GENP = [&](int s, uint4& o) {
    const unsigned bits = s_adjw[tr4 * 64 + s * 4 + th4];
    const float* ap = s_as + s * 32 + th4 * 8;
    unsigned wds[4];
#pragma unroll
    for (int p = 0; p < 4; ++p) {
      float z0 = adv + ap[2 * p];
      float z1 = adv + ap[2 * p + 1];
      z0 = fmaxf(z0, 0.2f * z0);
      z1 = fmaxf(z1, 0.2f * z1);
      float e0 = __expf(z0);
      float e1 = __expf(z1);
      e0 = ((bits >> (2 * p)) & 1u) ? e0 : 0.f;
      e1 = ((bits >> (2 * p + 1)) & 1u) ? e1 : 0.f;
      esum += e0 + e1;
      wds[p] = f2bf(e0) | (f2bf(e1) << 16);
    }
    o.x = wds[0]; o.y = wds[1]; o.z = wds[2]; o.w = wds[3];
  };
  auto BLOAD = [&](int s, uint4& r0, uint4& r1, uint4& r2, uint4& r3) {
    r0 = *(const uint4*)(xpTT + bBase0 + s * 32);
    r1 = *(const uint4*)(xpTT + bBase0 + s * 32 + 8);
    r2 = *(const uint4*)(xpTT + bBase1 + s * 32);
    r3 = *(const uint4*)(xpTT + bBase1 + s * 32 + 8);
  };

  GENP(0, pe);
  BLOAD(0, rb0, rb1, rb2, rb3);

  const f32x4 z4 = {0.f, 0.f, 0.f, 0.f};
  f32x4 acc[4][4];
#pragma unroll
  for (int fr = 0; fr < 4; ++fr)
#pragma unroll
    for (int fc = 0; fc < 4; ++fc) acc[fr][fc] = z4;

  for (int s = 0; s < 16; ++s) {
    const unsigned boff = (s & 1) ? 20480u : 0u;       // [A 4KB | B 16KB] per buffer
    *(uint4*)(lds + boff + wA) = pe;
    *(uint4*)(lds + boff + 4096 + wB0) = rb0;
    *(uint4*)(lds + boff + 4096 + wB1) = rb1;
    *(uint4*)(lds + boff + 4096 + wB0 + 8192) = rb2;   // rows 128..255
    *(uint4*)(lds + boff + 4096 + wB1 + 8192) = rb3;
    __syncthreads();
    if (s < 15) {
      BLOAD(s + 1, rb0, rb1, rb2, rb3);
      GENP(s + 1, pe);
    }
    bf16x8 af[4], bfr[4];
#pragma unroll
    for (int fr = 0; fr < 4; ++fr) {
      const int rA = fr * 16 + (lane & 15);            // rows 0..63, shared by all waves
      af[fr] = *(const bf16x8*)(lds + boff + rA * 64 +
                                (((lane >> 4) * 16) ^ (((rA >> 1) & 3) << 4)));
    }
#pragma unroll
    for (int fc = 0; fc < 4; ++fc) {
      const int rB = wk * 64 + fc * 16 + (lane & 15);  // rows 0..255
      bfr[fc] = *(const bf16x8*)(lds + boff + 4096 + rB * 64 +
                                 (((lane >> 4) * 16) ^ (((rB >> 1) & 3) << 4)));
    }
#pragma unroll
    for (int fr = 0; fr < 4; ++fr)
#pragma unroll
      for (int fc = 0; fc < 4; ++fc)
        acc[fr][fc] = __builtin_amdgcn_mfma_f32_16x16x32_bf16(af[fr], bfr[fc], acc[fr][fc], 0, 0, 0);
  }

  // denominator: reduce across th4 (4 lanes per row), publish dinv per local row
  esum += __shfl_xor(esum, 1);
  esum += __shfl_xor(esum, 2);
  __syncthreads();
  if (th4 == 0) s_dinv[tr4] = 1.f / (8.f * esum);
  __syncthreads();

  // ---- head-slice accumulation via device-scope atomics (coherence-point RMW) ----
  float* oa = out_acc + (size_t)b * NN * HH;
#pragma unroll
  for (int fr = 0; fr < 4; ++fr) {
    const int jl0 = fr * 16 + (lane >> 4) * 4;         // local row in [0,64)
#pragma unroll
    for (int fc = 0; fc < 4; ++fc) {
      const int kcol = wk * 64 + fc * 16 + (lane & 15);
#pragma unroll
      for (int rr = 0; rr < 4; ++rr)
        atomicAdd(&oa[(size_t)(j0 + jl0 + rr) * HH + kcol],
                  acc[fr][fc][rr] * s_dinv[jl0 + rr]);
    }
  }

  // ---- group tail: 8th arrival runs epilogue. __syncthreads drains all waves' vmcnt
  // (data atomics globally performed) before the counter bump. No spin, no bulk fence. ----
  __syncthreads();
  if (t == 0) {
    unsigned* c = cnt + b * 8 + jt;
    const unsigned old = __hip_atomic_fetch_add(c, 1u, __ATOMIC_RELAXED,
                                                __HIP_MEMORY_SCOPE_AGENT);
    s_last = (old == 7u) ? 1 : 0;
    if (old == 7u)
      __hip_atomic_store(c, 0u, __ATOMIC_RELAXED, __HIP_MEMORY_SCOPE_AGENT);  // self-reset
  }
  __syncthreads();
  if (!s_last) return;

  if (mode < 2) {
    // x += relu(out_acc + bias); x_bf = bf16(x); re-zero out_acc for next layer
#pragma unroll 4
    for (int rr = 0; rr < 64; ++rr) {
      const size_t idx = ((size_t)(b * NN + j0 + rr)) * HH + t;
      const float o = bias_l[t] + cohl(&out_acc[idx]);
      cohs(&out_acc[idx], 0.f);
      const float xn = x[idx] + fmaxf(o, 0.f);
      x[idx] = xn;
      x_bf[idx] = (unsigned short)f2bf(xn);
    }
  } else {
    // pass 1: y = emb + relu(x + relu(out_acc + bias)) -> out; re-zero out_acc
#pragma unroll 4
    for (int rr = 0; rr < 64; ++rr) {
      const size_t idx = ((size_t)(b * NN + j0 + rr)) * HH + t;
      const float o = bias_l[t] + cohl(&out_acc[idx]);
      cohs(&out_acc[idx], 0.f);
      const float xn = x[idx] + fmaxf(o, 0.f);
      out[idx] = emb[idx] + fmaxf(xn, 0.f);
    }
    __syncthreads();
    // pass 2: per-row mean/var (4 threads per row)
    {
      const int jr = t >> 2, q = t & 3;
      const size_t rb = ((size_t)(b * NN + j0 + jr)) * HH + q * 64;
      float s1 = 0.f, s2 = 0.f;
#pragma unroll 8
      for (int c = 0; c < 64; ++c) {
        const float y = out[rb + c];
        s1 += y;
        s2 += y * y;
      }
      s1 += __shfl_xor(s1, 1);
      s1 += __shfl_xor(s1, 2);
      s2 += __shfl_xor(s2, 1);
      s2 += __shfl_xor(s2, 2);
      if (q == 0) {
        const float mu = s1 * (1.f / 256.f);
        const float var = s2 * (1.f / 256.f) - mu * mu;
        s_mu[jr] = mu;
        s_rsig[jr] = rsqrtf(var + 1e-5f);
      }
    }
    __syncthreads();
    // pass 3: normalize (coalesced)
    const float g = gamma[t], be = beta[t];
#pragma unroll 4
    for (int rr = 0; rr < 64; ++rr) {
      const size_t idx = ((size_t)(b * NN + j0 + rr)) * HH + t;
      out[idx] = (out[idx] - s_mu[rr]) * s_rsig[rr] * g + be;
    }
  }
}

// ---------- host ----------
extern "C" void kernel_launch(void* const* d_in, const int* in_sizes, int n_in,
                              void* d_out, int out_size, void* d_ws, size_t ws_size,
                              hipStream_t stream) {
  const float* emb    = (const float*)d_in[0];
  const int*   mask   = (const int*)d_in[2];
  const float* W      = (const float*)d_in[4];
  const float* aw_src = (const float*)d_in[5];
  const float* aw_dst = (const float*)d_in[6];
  const float* bias   = (const float*)d_in[7];
  const float* gamma  = (const float*)d_in[8];
  const float* beta   = (const float*)d_in[9];
  float* out = (float*)d_out;

  char* ws = (char*)d_ws;
  unsigned short* xpTT = (unsigned short*)(ws);             // 16,777,216 B
  float* out_acc       = (float*)(ws + 16777216);           //  4,194,304 B
  float* x             = (float*)(ws + 20971520);           //  4,194,304 B
  unsigned short* x_bf = (unsigned short*)(ws + 25165824);  //  2,097,152 B
  float* asrcT         = (float*)(ws + 27262976);           //    393,216 B (3 layers)
  float* adstT         = (float*)(ws + 27656192);           //    393,216 B (3 layers)
  unsigned long long* adjT = (unsigned long long*)(ws + 28049408);  // 262,144 B
  unsigned short* Wt   = (unsigned short*)(ws + 28311552);  //  3,145,728 B
  unsigned* cnt        = (unsigned*)(ws + 31457280);        //        256 B

  prologue_kernel<<<3136, 256, 0, stream>>>(emb, mask, W, x, x_bf, adjT, Wt,
                                            asrcT, adstT, out_acc, cnt);

  for (int l = 0; l < 3; ++l) {
    float* asrc_l = asrcT + (size_t)l * 32768;
    float* adst_l = adstT + (size_t)l * 32768;
    proj_mfma_kernel<<<512, 256, 0, stream>>>(Wt + (size_t)l * 524288, x_bf,
                                              aw_src + l * NHEADS * HH, aw_dst + l * NHEADS * HH,
                                              xpTT, asrc_l, adst_l);
    agg_fused_kernel<<<512, 256, 0, stream>>>(xpTT, asrc_l, adst_l, adjT, out_acc,
                                              bias + l * HH, x, x_bf, emb, gamma, beta, out,
                                              cnt, l);
  }
}

// Round 15
// 115.781 us; speedup vs baseline: 2.6760x; 2.6760x over previous
//
#include <hip/hip_runtime.h>

#define BB 8
#define NN 512
#define HH 256
#define NHEADS 8

typedef __attribute__((ext_vector_type(8))) short bf16x8;
typedef __attribute__((ext_vector_type(4))) float f32x4;

// ---------- helpers ----------
__device__ __forceinline__ unsigned f2bf(float f) {
  unsigned u = __float_as_uint(f);
  u += 0x7fffu + ((u >> 16) & 1u);          // round-to-nearest-even
  return u >> 16;
}
__device__ __forceinline__ float bf2f(unsigned short v) {
  return __uint_as_float(((unsigned)v) << 16);
}

// ---------- kernel 0: fused prologue: x_bf init | adjacency | transpose W | zero asrc/adst ----------
// x itself is NOT materialized (epi(0) reads emb directly; x is first written by epi(0)).
__global__ __launch_bounds__(256) void prologue_kernel(const float* __restrict__ emb,
                                                       const int* __restrict__ mask,
                                                       const float* __restrict__ W,
                                                       unsigned short* __restrict__ x_bf,
                                                       unsigned long long* __restrict__ adjT,
                                                       unsigned short* __restrict__ Wt,
                                                       float* __restrict__ asrcT,
                                                       float* __restrict__ adstT) {
  __shared__ float s[64][65];
  __shared__ unsigned short sadj[4][64];
  const int bid = blockIdx.x;
  const int t = threadIdx.x;
  if (bid < 1024) {                        // ---- init x_bf (bf16), XCD-pinned by b ----
    const int b = bid & 7, chunk = bid >> 3;           // 128 chunks per b
    const size_t i4 = ((size_t)b * 128 + chunk) * 256 + t;   // float4 index
    const float4 v = ((const float4*)emb)[i4];
    uint2 p;
    p.x = f2bf(v.x) | (f2bf(v.y) << 16);
    p.y = f2bf(v.z) | (f2bf(v.w) << 16);
    ((uint2*)x_bf)[i4] = p;
  } else if (bid < 1536) {                 // ---- adjT[b][j][w] bit q <=> edge i=64w+q -> j ----
    const int bb = bid - 1024;             // 512 blocks = (b = bb&7, w, jc)
    const int b = bb & 7, w = (bb >> 3) & 7, jc = bb >> 6;
    const int jloc = t & 63, qq = t >> 6;  // 4 q-quarters of 16
    const int j = jc * 64 + jloc;
    unsigned short bits = 0;
#pragma unroll
    for (int qi = 0; qi < 16; ++qi) {
      const int q = qq * 16 + qi;
      const int i = w * 64 + q;
      const int m = mask[((size_t)b * NN + i) * NN + j];   // coalesced across jloc
      if (m != 0 || i == j) bits |= (unsigned short)(1u << qi);
    }
    sadj[qq][jloc] = bits;
    __syncthreads();
    if (t < 64) {
      const unsigned long long word = (unsigned long long)sadj[0][t] |
                                      ((unsigned long long)sadj[1][t] << 16) |
                                      ((unsigned long long)sadj[2][t] << 32) |
                                      ((unsigned long long)sadj[3][t] << 48);
      adjT[((size_t)b * NN + jc * 64 + t) * 8 + w] = word;
    }
  } else if (bid < 1920) {                 // ---- Wt[l][hk][c] (bf16) = W[l][c][hk] ----
    const int wb = bid - 1536;
    const int l = wb >> 7;
    const int r = wb & 127;
    const int mt = r & 31, ct = r >> 5;
    const int hk0 = mt * 64, c0 = ct * 64;
    const int tr = t >> 6, tc = t & 63;
#pragma unroll
    for (int p = 0; p < 16; ++p) {
      const int row = p * 4 + tr;
      s[row][tc] = W[(size_t)l * 524288 + (size_t)(c0 + row) * 2048 + hk0 + tc];
    }
    __syncthreads();
#pragma unroll
    for (int p = 0; p < 16; ++p) {
      const int hkl = p * 4 + tr;
      Wt[(size_t)l * 524288 + (size_t)(hk0 + hkl) * 256 + c0 + tc] =
          (unsigned short)f2bf(s[tc][hkl]);
    }
  } else {                                 // ---- zero asrcT + adstT (layer 0) ----
    const int i4 = (bid - 1920) * 256 + t;           // 0..16383
    const float4 z = {0.f, 0.f, 0.f, 0.f};
    if (i4 < 8192) ((float4*)asrcT)[i4] = z;
    else           ((float4*)adstT)[i4 - 8192] = z;
  }
}

// ---------- kernel 1: proj via MFMA + fused a_src/a_dst partial reduction ----------
// Double-buffered LDS: ONE barrier per K-step. Coalesced C-store via LDS restage.
// grid 512 = (b:8, mt:16, nt:4). 128x128 tile, K=256 in 8 steps of 32. 4 waves 64x64.
__global__ __launch_bounds__(256, 2) void proj_mfma_kernel(const unsigned short* __restrict__ Wt_l,
                                                           const unsigned short* __restrict__ x_bf,
                                                           const float* __restrict__ att_src_l,
                                                           const float* __restrict__ att_dst_l,
                                                           unsigned short* __restrict__ xpTT,
                                                           float* __restrict__ asrcT,
                                                           float* __restrict__ adstT) {
  __shared__ __align__(16) unsigned char lds[32768];   // [buf:2][A 8KB | B 8KB]; reused as C tile
  const int t = threadIdx.x;
  const int lane = t & 63, wave = t >> 6;
  const int wj = wave >> 1, wk = wave & 1;

  const int bid = blockIdx.x;
  const int b = bid & 7;                  // same-b -> same XCD L2 as agg consumer
  const int r = bid >> 3;
  const int mt = r & 15, nt = r >> 4;
  const int hk0 = mt * 128, n0 = nt * 128;

  const int tr = t >> 1, th = t & 1;
  const size_t aBase = (size_t)(hk0 + tr) * 256 + th * 16;
  const size_t bBase = ((size_t)(b * NN + n0 + tr)) * 256 + th * 16;
  const unsigned sw_w = ((tr >> 1) & 3) << 4;
  const unsigned w0 = tr * 64 + ((th * 32 + 0) ^ sw_w);
  const unsigned w1 = tr * 64 + ((th * 32 + 16) ^ sw_w);

  uint4 ra0, ra1, rb0, rb1;
  {
    ra0 = *(const uint4*)(Wt_l + aBase);
    ra1 = *(const uint4*)(Wt_l + aBase + 8);
    rb0 = *(const uint4*)(x_bf + bBase);
    rb1 = *(const uint4*)(x_bf + bBase + 8);
  }

  const f32x4 z4 = {0.f, 0.f, 0.f, 0.f};
  f32x4 acc[4][4];
#pragma unroll
  for (int fr = 0; fr < 4; ++fr)
#pragma unroll
    for (int fc = 0; fc < 4; ++fc) acc[fr][fc] = z4;

  for (int s = 0; s < 8; ++s) {
    const unsigned boff = (s & 1) << 14;               // 0 / 16384
    *(uint4*)(lds + boff + w0) = ra0;                  // A
    *(uint4*)(lds + boff + w1) = ra1;
    *(uint4*)(lds + boff + 8192 + w0) = rb0;           // B
    *(uint4*)(lds + boff + 8192 + w1) = rb1;
    __syncthreads();
    if (s < 7) {
      const size_t off = (size_t)(s + 1) * 32;
      ra0 = *(const uint4*)(Wt_l + aBase + off);
      ra1 = *(const uint4*)(Wt_l + aBase + off + 8);
      rb0 = *(const uint4*)(x_bf + bBase + off);
      rb1 = *(const uint4*)(x_bf + bBase + off + 8);
    }
    bf16x8 af[4], bfr[4];
#pragma unroll
    for (int fr = 0; fr < 4; ++fr) {
      const int rA = wj * 64 + fr * 16 + (lane & 15);
      af[fr] = *(const bf16x8*)(lds + boff + rA * 64 +
                                (((lane >> 4) * 16) ^ (((rA >> 1) & 3) << 4)));
    }
#pragma unroll
    for (int fc = 0; fc < 4; ++fc) {
      const int rB = wk * 64 + fc * 16 + (lane & 15);
      bfr[fc] = *(const bf16x8*)(lds + boff + 8192 + rB * 64 +
                                 (((lane >> 4) * 16) ^ (((rB >> 1) & 3) << 4)));
    }
#pragma unroll
    for (int fr = 0; fr < 4; ++fr)
#pragma unroll
      for (int fc = 0; fc < 4; ++fc)
        acc[fr][fc] = __builtin_amdgcn_mfma_f32_16x16x32_bf16(af[fr], bfr[fc], acc[fr][fc], 0, 0, 0);
  }

  // ---- restage C tile (bf16) into LDS, then write coalesced rows ----
  __syncthreads();                         // all waves done reading K-loop LDS
  unsigned short* sc = (unsigned short*)lds;           // [128 rows][128 cols] = 32 KB
  const int lr = lane & 15, lo = lane >> 4;
#pragma unroll
  for (int fr = 0; fr < 4; ++fr) {
    const int rowl0 = wj * 64 + fr * 16 + lo * 4;
#pragma unroll
    for (int fc = 0; fc < 4; ++fc) {
      const int coll = wk * 64 + fc * 16 + lr;
#pragma unroll
      for (int rr = 0; rr < 4; ++rr)
        sc[(rowl0 + rr) * 128 + coll] = (unsigned short)f2bf(acc[fr][fc][rr]);
    }
  }
  __syncthreads();
  unsigned short* xpb = xpTT + (size_t)b * 2048 * NN;
#pragma unroll
  for (int p = 0; p < 8; ++p) {
    const int idx4 = p * 256 + t;          // uint4 index in tile (2048 total)
    const int row = idx4 >> 4;             // 16 uint4 per 128-col row
    const int c4 = idx4 & 15;
    *(uint4*)(xpb + (size_t)(hk0 + row) * NN + n0 + c4 * 8) = *(const uint4*)(sc + idx4 * 8);
  }

  // ---- fused a_src/a_dst: block covers head h = mt>>1 (128 hk rows within one head) ----
  float wsv[4][4], wdv[4][4];
#pragma unroll
  for (int fr = 0; fr < 4; ++fr) {
    const int row0 = hk0 + wj * 64 + fr * 16 + lo * 4;
#pragma unroll
    for (int rr = 0; rr < 4; ++rr) {
      wsv[fr][rr] = att_src_l[row0 + rr];
      wdv[fr][rr] = att_dst_l[row0 + rr];
    }
  }
  const int bh = b * 8 + (mt >> 1);
#pragma unroll
  for (int fc = 0; fc < 4; ++fc) {
    float as = 0.f, ad = 0.f;
#pragma unroll
    for (int fr = 0; fr < 4; ++fr)
#pragma unroll
      for (int rr = 0; rr < 4; ++rr) {
        as = fmaf(acc[fr][fc][rr], wsv[fr][rr], as);
        ad = fmaf(acc[fr][fc][rr], wdv[fr][rr], ad);
      }
    as += __shfl_xor(as, 16);
    as += __shfl_xor(as, 32);
    ad += __shfl_xor(ad, 16);
    ad += __shfl_xor(ad, 32);
    if ((lane >> 4) == 0) {
      const int col = n0 + wk * 64 + fc * 16 + lane;   // lane in [0,16)
      atomicAdd(&asrcT[(size_t)bh * NN + col], as);
      atomicAdd(&adstT[(size_t)bh * NN + col], ad);
    }
  }
}

// ---------- kernel 2: fused agg, one head per block, full k=256, K-step=32, double-buffered LDS ----------
// grid 512 = (b:8, jt:8, hs:8). 64j x 256k tile, K=512 in 16 steps.
// 4 waves = wk:4, each 64j x 64k. out_part stored BF16 (per-b slice 2 MB -> L2-resident).
__global__ __launch_bounds__(256, 2) void agg_fused_kernel(const unsigned short* __restrict__ xpTT,
                                                           const float* __restrict__ asrcT,
                                                           const float* __restrict__ adstT,
                                                           const unsigned long long* __restrict__ adjT,
                                                           unsigned short* __restrict__ out_part) {
  __shared__ __align__(16) unsigned char lds[40960];    // [buf:2][A 4KB | B 16KB]
  __shared__ float s_as[NN];                            // a_src, head hs
  __shared__ __align__(16) unsigned char s_adjw[4096];  // adjacency rows j0..j0+64 (64 B each)
  __shared__ float s_dinv[64];
  const int t = threadIdx.x;
  const int lane = t & 63, wave = t >> 6;
  const int wk = wave;                    // wave owns k-columns wk*64..wk*64+64

  const int bid = blockIdx.x;
  const int b = bid & 7;
  const int r = bid >> 3;
  const int jt = r & 7, hs = r >> 3;
  const int j0 = jt * 64;
  const int bh = b * 8 + hs;

  const int tr4 = t >> 2, th4 = t & 3;   // A staging + GENP: row tr4 (0..63), i-octet th4
  const int tr2 = t >> 1, th2 = t & 1;   // B staging: rows tr2 and tr2+128, i-half th2

  // stage a_src + adjacency rows
  s_as[t] = asrcT[(size_t)bh * NN + t];
  s_as[t + 256] = asrcT[(size_t)bh * NN + t + 256];
  *(uint4*)(s_adjw + tr4 * 64 + th4 * 16) =
      *(const uint4*)((const unsigned char*)adjT + ((size_t)(b * NN + j0 + tr4)) * 64 + th4 * 16);
  const float adv = adstT[(size_t)bh * NN + j0 + tr4];
  __syncthreads();

  const unsigned sw4 = ((tr4 >> 1) & 3) << 4;
  const unsigned wA = tr4 * 64 + ((th4 * 16) ^ sw4);
  const unsigned sw2 = ((tr2 >> 1) & 3) << 4;          // same swizzle for row tr2 and tr2+128
  const unsigned wB0 = tr2 * 64 + ((th2 * 32 + 0) ^ sw2);
  const unsigned wB1 = tr2 * 64 + ((th2 * 32 + 16) ^ sw2);
  const size_t bBase0 = ((size_t)bh * HH + tr2) * NN + th2 * 16;        // row tr2
  const size_t bBase1 = ((size_t)bh * HH + tr2 + 128) * NN + th2 * 16;  // row tr2+128

  float esum = 0.f;                       // running denominator, row tr4, this th4 i-octet set
  uint4 pe, rb0, rb1, rb2, rb3;
  auto GENP = [&](int s, uint4& o) {
    const unsigned bits = s_adjw[tr4 * 64 + s * 4 + th4];
    const float* ap = s_as + s * 32 + th4 * 8;
    unsigned wds[4];
#pragma unroll
    for (int p = 0; p < 4; ++p) {
      float z0 = adv + ap[2 * p];
      float z1 = adv + ap[2 * p + 1];
      z0 = fmaxf(z0, 0.2f * z0);
      z1 = fmaxf(z1, 0.2f * z1);
      float e0 = __expf(z0);
      float e1 = __expf(z1);
      e0 = ((bits >> (2 * p)) & 1u) ? e0 : 0.f;
      e1 = ((bits >> (2 * p + 1)) & 1u) ? e1 : 0.f;
      esum += e0 + e1;
      wds[p] = f2bf(e0) | (f2bf(e1) << 16);
    }
    o.x = wds[0]; o.y = wds[1]; o.z = wds[2]; o.w = wds[3];
  };
  auto BLOAD = [&](int s, uint4& r0, uint4& r1, uint4& r2, uint4& r3) {
    r0 = *(const uint4*)(xpTT + bBase0 + s * 32);
    r1 = *(const uint4*)(xpTT + bBase0 + s * 32 + 8);
    r2 = *(const uint4*)(xpTT + bBase1 + s * 32);
    r3 = *(const uint4*)(xpTT + bBase1 + s * 32 + 8);
  };

  GENP(0, pe);
  BLOAD(0, rb0, rb1, rb2, rb3);

  const f32x4 z4 = {0.f, 0.f, 0.f, 0.f};
  f32x4 acc[4][4];
#pragma unroll
  for (int fr = 0; fr < 4; ++fr)
#pragma unroll
    for (int fc = 0; fc < 4; ++fc) acc[fr][fc] = z4;

  for (int s = 0; s < 16; ++s) {
    const unsigned boff = (s & 1) ? 20480u : 0u;       // [A 4KB | B 16KB] per buffer
    *(uint4*)(lds + boff + wA) = pe;
    *(uint4*)(lds + boff + 4096 + wB0) = rb0;
    *(uint4*)(lds + boff + 4096 + wB1) = rb1;
    *(uint4*)(lds + boff + 4096 + wB0 + 8192) = rb2;   // rows 128..255
    *(uint4*)(lds + boff + 4096 + wB1 + 8192) = rb3;
    __syncthreads();
    if (s < 15) {
      BLOAD(s + 1, rb0, rb1, rb2, rb3);
      GENP(s + 1, pe);
    }
    bf16x8 af[4], bfr[4];
#pragma unroll
    for (int fr = 0; fr < 4; ++fr) {
      const int rA = fr * 16 + (lane & 15);            // rows 0..63, shared by all waves
      af[fr] = *(const bf16x8*)(lds + boff + rA * 64 +
                                (((lane >> 4) * 16) ^ (((rA >> 1) & 3) << 4)));
    }
#pragma unroll
    for (int fc = 0; fc < 4; ++fc) {
      const int rB = wk * 64 + fc * 16 + (lane & 15);  // rows 0..255
      bfr[fc] = *(const bf16x8*)(lds + boff + 4096 + rB * 64 +
                                 (((lane >> 4) * 16) ^ (((rB >> 1) & 3) << 4)));
    }
#pragma unroll
    for (int fr = 0; fr < 4; ++fr)
#pragma unroll
      for (int fc = 0; fc < 4; ++fc)
        acc[fr][fc] = __builtin_amdgcn_mfma_f32_16x16x32_bf16(af[fr], bfr[fc], acc[fr][fc], 0, 0, 0);
  }

  // denominator: reduce across th4 (4 lanes per row), publish dinv per local row
  esum += __shfl_xor(esum, 1);
  esum += __shfl_xor(esum, 2);
  __syncthreads();
  if (th4 == 0) s_dinv[tr4] = 1.f / (8.f * esum);
  __syncthreads();

  unsigned short* op = out_part + ((size_t)hs * BB + b) * NN * HH;
#pragma unroll
  for (int fr = 0; fr < 4; ++fr) {
    const int jl0 = fr * 16 + (lane >> 4) * 4;         // local row in [0,64)
#pragma unroll
    for (int fc = 0; fc < 4; ++fc) {
      const int kcol = wk * 64 + fc * 16 + (lane & 15);
#pragma unroll
      for (int rr = 0; rr < 4; ++rr)
        op[(size_t)(j0 + jl0 + rr) * HH + kcol] =
            (unsigned short)f2bf(acc[fr][fc][rr] * s_dinv[jl0 + rr]);
    }
  }
}

// ---------- kernel 3: epilogue (layers 0,1), XCD-pinned: b = bid&7.
// x = xin + relu(sum_8 bf16 out_part + bias); x_bf = bf16(x); xin = emb for l=0, else x.
// Blocks 0..63 also zero asrcT/adstT for the next layer's proj. ----------
__global__ __launch_bounds__(256) void out_epi_kernel(const unsigned short* __restrict__ out_part,
                                                      const float* __restrict__ bias_l,
                                                      const float* __restrict__ xin,
                                                      float* __restrict__ x,
                                                      unsigned short* __restrict__ x_bf,
                                                      float* __restrict__ asrcT,
                                                      float* __restrict__ adstT) {
  const int bid = blockIdx.x;
  const int t = threadIdx.x;
  if (bid < 64) {                          // zero asrc/adst for next layer
    const int i4 = bid * 256 + t;          // 0..16383
    const float4 z = {0.f, 0.f, 0.f, 0.f};
    if (i4 < 8192) ((float4*)asrcT)[i4] = z;
    else           ((float4*)adstT)[i4 - 8192] = z;
  }
  const int b = bid & 7, nn = bid >> 3;    // same XCD as agg producer of this b
  const size_t idx = ((size_t)(b * NN + nn)) * HH + t;
  const size_t S = (size_t)BB * NN * HH;
  float o = bias_l[t];
#pragma unroll
  for (int s = 0; s < 8; ++s) o += bf2f(out_part[s * S + idx]);
  const float xn = xin[idx] + fmaxf(o, 0.f);
  x[idx] = xn;
  x_bf[idx] = (unsigned short)f2bf(xn);
}

// ---------- kernel 4: fused last-layer epilogue + final LayerNorm, XCD-pinned ----------
__global__ __launch_bounds__(256) void epi_ln_kernel(const unsigned short* __restrict__ out_part,
                                                     const float* __restrict__ bias_l,
                                                     const float* __restrict__ x,
                                                     const float* __restrict__ emb,
                                                     const float* __restrict__ gamma,
                                                     const float* __restrict__ beta,
                                                     float* __restrict__ out) {
  const int bid = blockIdx.x;
  const int t = threadIdx.x;
  const int b = bid & 7, nn = bid >> 3;
  const size_t idx = ((size_t)(b * NN + nn)) * HH + t;
  const size_t S = (size_t)BB * NN * HH;
  float o = bias_l[t];
#pragma unroll
  for (int s = 0; s < 8; ++s) o += bf2f(out_part[s * S + idx]);
  const float xn = x[idx] + fmaxf(o, 0.f);
  const float y = emb[idx] + fmaxf(xn, 0.f);
  float s1 = y, s2 = y * y;
#pragma unroll
  for (int off = 32; off > 0; off >>= 1) {
    s1 += __shfl_down(s1, off);
    s2 += __shfl_down(s2, off);
  }
  __shared__ float rs[4], rs2[4], stat[2];
  const int wave = t >> 6, lane = t & 63;
  if (lane == 0) { rs[wave] = s1; rs2[wave] = s2; }
  __syncthreads();
  if (t == 0) {
    const float S1 = rs[0] + rs[1] + rs[2] + rs[3];
    const float S2 = rs2[0] + rs2[1] + rs2[2] + rs2[3];
    const float mu = S1 * (1.f / 256.f);
    const float var = S2 * (1.f / 256.f) - mu * mu;
    stat[0] = mu;
    stat[1] = rsqrtf(var + 1e-5f);
  }
  __syncthreads();
  out[idx] = (y - stat[0]) * stat[1] * gamma[t] + beta[t];
}

// ---------- host ----------
extern "C" void kernel_launch(void* const* d_in, const int* in_sizes, int n_in,
                              void* d_out, int out_size, void* d_ws, size_t ws_size,
                              hipStream_t stream) {
  const float* emb    = (const float*)d_in[0];
  const int*   mask   = (const int*)d_in[2];
  const float* W      = (const float*)d_in[4];
  const float* aw_src = (const float*)d_in[5];
  const float* aw_dst = (const float*)d_in[6];
  const float* bias   = (const float*)d_in[7];
  const float* gamma  = (const float*)d_in[8];
  const float* beta   = (const float*)d_in[9];
  float* out = (float*)d_out;

  char* ws = (char*)d_ws;
  unsigned short* xpTT = (unsigned short*)(ws);             // 16,777,216 B
  unsigned short* out_part = (unsigned short*)(ws + 16777216);  // 16,777,216 B (8 bf16 slices)
  float* x             = (float*)(ws + 50331648);           //  4,194,304 B
  unsigned short* x_bf = (unsigned short*)(ws + 54525952);  //  2,097,152 B
  float* asrcT         = (float*)(ws + 56623104);           //    131,072 B
  float* adstT         = (float*)(ws + 56754176);           //    131,072 B
  unsigned long long* adjT = (unsigned long long*)(ws + 57016320);  // 262,144 B
  unsigned short* Wt   = (unsigned short*)(ws + 57278464);  //  3,145,728 B

  prologue_kernel<<<1984, 256, 0, stream>>>(emb, mask, W, x_bf, adjT, Wt, asrcT, adstT);

  for (int l = 0; l < 3; ++l) {
    proj_mfma_kernel<<<512, 256, 0, stream>>>(Wt + (size_t)l * 524288, x_bf,
                                              aw_src + l * NHEADS * HH, aw_dst + l * NHEADS * HH,
                                              xpTT, asrcT, adstT);
    agg_fused_kernel<<<512, 256, 0, stream>>>(xpTT, asrcT, adstT, adjT, out_part);
    if (l < 2)
      out_epi_kernel<<<BB * NN, 256, 0, stream>>>(out_part, bias + l * HH,
                                                  l == 0 ? emb : x, x, x_bf, asrcT, adstT);
  }
  epi_ln_kernel<<<BB * NN, 256, 0, stream>>>(out_part, bias + 2 * HH, x, emb, gamma, beta, out);
}